// Round 4
// baseline (2564.242 us; speedup 1.0000x reference)
//
#include <hip/hip_runtime.h>
#include <hip/hip_bf16.h>

#define B_ 256
#define T_ 2048
#define I_ 64
#define H_ 128
#define G_ 384   // 3*H
#define O_ 10

typedef _Float16 half2_t __attribute__((ext_vector_type(2)));
typedef _Float16 half8_t __attribute__((ext_vector_type(8)));

__device__ __forceinline__ float sigm_(float s) {
  s = fminf(fmaxf(s, -30.f), 30.f);
  return __builtin_amdgcn_rcpf(1.f + __expf(-s));
}
// tanh(s) = 1 - 2/(1+e^{2s})
__device__ __forceinline__ float tanh_(float s) {
  s = fminf(fmaxf(s, -15.f), 15.f);
  return 1.f - 2.f * __builtin_amdgcn_rcpf(1.f + __expf(2.f * s));
}

// 8 fp32 -> one named half8 SSA value (4 VGPRs). Named vectors, no arrays:
// R1/R2 showed half2_t wi[64] arrays defeat SROA -> permanent scratch.
#define LOADW(DST, SRC) do { const float* s_ = (SRC); half8_t w_; \
  w_[0]=(_Float16)s_[0]; w_[1]=(_Float16)s_[1]; w_[2]=(_Float16)s_[2]; w_[3]=(_Float16)s_[3]; \
  w_[4]=(_Float16)s_[4]; w_[5]=(_Float16)s_[5]; w_[6]=(_Float16)s_[6]; w_[7]=(_Float16)s_[7]; \
  (DST) = w_; } while(0)

// 4 fdot2 into 4 accumulators; constant even-lane half2 extraction is a pure
// subregister reference (half8 = 4 VGPRs, pair j = VGPR j).
#define D8(S0,S1,S2,S3,W,XV) do { half8_t xv_ = (XV); half8_t w_ = (W); \
  S0 = __builtin_amdgcn_fdot2(__builtin_shufflevector(w_,w_,0,1), __builtin_shufflevector(xv_,xv_,0,1), (S0), false); \
  S1 = __builtin_amdgcn_fdot2(__builtin_shufflevector(w_,w_,2,3), __builtin_shufflevector(xv_,xv_,2,3), (S1), false); \
  S2 = __builtin_amdgcn_fdot2(__builtin_shufflevector(w_,w_,4,5), __builtin_shufflevector(xv_,xv_,4,5), (S2), false); \
  S3 = __builtin_amdgcn_fdot2(__builtin_shufflevector(w_,w_,6,7), __builtin_shufflevector(xv_,xv_,6,7), (S3), false); \
} while(0)

// CONVERGENT BARRIERS: R3 put __syncthreads() inside divergent role branches
// (spec-UB; works only if both paths emit balanced s_barrier counts). R3's
// codegen unbalanced them -> replay-dependent race (first validation passed,
// post-timing absmax 0.216). This version has ONE loop executed by ALL
// threads; barriers at loop scope; role divergence only between barriers.
// Both roles share the same 32 named half8 weight regs (role0 leaves a8..a15
// zero) so register liveness stays ~158 < 170 (launch_bounds(768,3) budget).
__global__ __launch_bounds__(768, 3) void gru_net(
    const float* __restrict__ x,
    const float* __restrict__ Wih0, const float* __restrict__ Whh0,
    const float* __restrict__ bih0, const float* __restrict__ bhh0,
    const float* __restrict__ Wih1, const float* __restrict__ Whh1,
    const float* __restrict__ bih1, const float* __restrict__ bhh1,
    const float* __restrict__ fcW, const float* __restrict__ fcb,
    float* __restrict__ out)
{
  const int b   = blockIdx.x;
  const int tid = threadIdx.x;

  __shared__ alignas(16) half2_t xp[2][I_/2];    // x_t fp16, double-buffered
  __shared__ alignas(16) half2_t h0p[2][H_/2];   // h0 fp16, double-buffered
  __shared__ alignas(16) half2_t h1p[2][H_/2];   // h1 fp16, double-buffered
  __shared__ float h0f[H_], h1f[H_];             // fp32 hidden states
  __shared__ float rz0[2*H_], rz1[2*H_];         // r,z gate values

  const size_t xbase = (size_t)b * T_ * I_;

  // ---- init shared state ----
  if (tid < H_) { h0f[tid] = 0.f; h1f[tid] = 0.f; }
  if (tid < H_/2) {
    half2_t z2; z2[0] = (_Float16)0.f; z2[1] = (_Float16)0.f;
    h0p[0][tid] = z2; h0p[1][tid] = z2;
    h1p[0][tid] = z2; h1p[1][tid] = z2;
  }
  if (tid < I_) {
    ((_Float16*)xp[0])[tid] = (_Float16)x[xbase + tid];
  }
  __syncthreads();

  const bool r0 = (tid < G_);            // role: layer-0 vs layer-1 (lag 1)
  const int  g  = r0 ? tid : tid - G_;   // gate index within layer

  // Unified weight registers (32 x half8 = 128 VGPRs, shared by both roles).
  half8_t a0{},a1{},a2{},a3{},a4{},a5{},a6{},a7{},
          a8{},a9{},a10{},a11{},a12{},a13{},a14{},a15{};
  half8_t w0{},w1{},w2{},w3{},w4{},w5{},w6{},w7{},
          w8{},w9{},w10{},w11{},w12{},w13{},w14{},w15{};
  float bi, bh;
  if (r0) {
    const float* p0 = Wih0 + (size_t)g * I_;
    LOADW(a0,p0+ 0); LOADW(a1,p0+ 8); LOADW(a2,p0+16); LOADW(a3,p0+24);
    LOADW(a4,p0+32); LOADW(a5,p0+40); LOADW(a6,p0+48); LOADW(a7,p0+56);
    const float* p1 = Whh0 + (size_t)g * H_;
    LOADW(w0 ,p1+  0); LOADW(w1 ,p1+  8); LOADW(w2 ,p1+ 16); LOADW(w3 ,p1+ 24);
    LOADW(w4 ,p1+ 32); LOADW(w5 ,p1+ 40); LOADW(w6 ,p1+ 48); LOADW(w7 ,p1+ 56);
    LOADW(w8 ,p1+ 64); LOADW(w9 ,p1+ 72); LOADW(w10,p1+ 80); LOADW(w11,p1+ 88);
    LOADW(w12,p1+ 96); LOADW(w13,p1+104); LOADW(w14,p1+112); LOADW(w15,p1+120);
    bi = bih0[g]; bh = bhh0[g];
  } else {
    const float* p0 = Wih1 + (size_t)g * H_;
    LOADW(a0 ,p0+  0); LOADW(a1 ,p0+  8); LOADW(a2 ,p0+ 16); LOADW(a3 ,p0+ 24);
    LOADW(a4 ,p0+ 32); LOADW(a5 ,p0+ 40); LOADW(a6 ,p0+ 48); LOADW(a7 ,p0+ 56);
    LOADW(a8 ,p0+ 64); LOADW(a9 ,p0+ 72); LOADW(a10,p0+ 80); LOADW(a11,p0+ 88);
    LOADW(a12,p0+ 96); LOADW(a13,p0+104); LOADW(a14,p0+112); LOADW(a15,p0+120);
    const float* p1 = Whh1 + (size_t)g * H_;
    LOADW(w0 ,p1+  0); LOADW(w1 ,p1+  8); LOADW(w2 ,p1+ 16); LOADW(w3 ,p1+ 24);
    LOADW(w4 ,p1+ 32); LOADW(w5 ,p1+ 40); LOADW(w6 ,p1+ 48); LOADW(w7 ,p1+ 56);
    LOADW(w8 ,p1+ 64); LOADW(w9 ,p1+ 72); LOADW(w10,p1+ 80); LOADW(w11,p1+ 88);
    LOADW(w12,p1+ 96); LOADW(w13,p1+104); LOADW(w14,p1+112); LOADW(w15,p1+120);
    bi = bih1[g]; bh = bhh1[g];
  }

  // Role-selected LDS pointers, hoisted (divergent but loop-invariant).
  float* rzW = r0 ? rz0 : rz1;
  float* hfW = r0 ? h0f : h1f;
  _Float16* hpW0 = (_Float16*)(r0 ? h0p[0] : h1p[0]);
  _Float16* hpW1 = (_Float16*)(r0 ? h0p[1] : h1p[1]);

  for (int p = 0; p <= T_; ++p) {
    float ax = 0.f, ah = 0.f, xnext = 0.f;
    const bool act = r0 ? (p < T_) : (p >= 1);
    if (act) {
      const half8_t* hA = (const half8_t*)h0p[(p & 1) ^ 1];  // h0 prev phase
      float s0=0.f, s1=0.f, s2=0.f, s3=0.f;
      float c0=0.f, c1=0.f, c2=0.f, c3=0.f;
      if (r0) {
        if (g < I_ && p + 1 < T_) xnext = x[xbase + (size_t)(p + 1) * I_ + g];
        const half8_t* xr = (const half8_t*)xp[p & 1];
        D8(s0,s1,s2,s3, a0, xr[0]); D8(s0,s1,s2,s3, a1, xr[1]);
        D8(s0,s1,s2,s3, a2, xr[2]); D8(s0,s1,s2,s3, a3, xr[3]);
        D8(s0,s1,s2,s3, a4, xr[4]); D8(s0,s1,s2,s3, a5, xr[5]);
        D8(s0,s1,s2,s3, a6, xr[6]); D8(s0,s1,s2,s3, a7, xr[7]);
        D8(c0,c1,c2,c3, w0 , hA[ 0]); D8(c0,c1,c2,c3, w1 , hA[ 1]);
        D8(c0,c1,c2,c3, w2 , hA[ 2]); D8(c0,c1,c2,c3, w3 , hA[ 3]);
        D8(c0,c1,c2,c3, w4 , hA[ 4]); D8(c0,c1,c2,c3, w5 , hA[ 5]);
        D8(c0,c1,c2,c3, w6 , hA[ 6]); D8(c0,c1,c2,c3, w7 , hA[ 7]);
        D8(c0,c1,c2,c3, w8 , hA[ 8]); D8(c0,c1,c2,c3, w9 , hA[ 9]);
        D8(c0,c1,c2,c3, w10, hA[10]); D8(c0,c1,c2,c3, w11, hA[11]);
        D8(c0,c1,c2,c3, w12, hA[12]); D8(c0,c1,c2,c3, w13, hA[13]);
        D8(c0,c1,c2,c3, w14, hA[14]); D8(c0,c1,c2,c3, w15, hA[15]);
      } else {
        const half8_t* h1r = (const half8_t*)h1p[(p & 1) ^ 1];  // h1(p-2)
        D8(s0,s1,s2,s3, a0 , hA[ 0]); D8(s0,s1,s2,s3, a1 , hA[ 1]);
        D8(s0,s1,s2,s3, a2 , hA[ 2]); D8(s0,s1,s2,s3, a3 , hA[ 3]);
        D8(s0,s1,s2,s3, a4 , hA[ 4]); D8(s0,s1,s2,s3, a5 , hA[ 5]);
        D8(s0,s1,s2,s3, a6 , hA[ 6]); D8(s0,s1,s2,s3, a7 , hA[ 7]);
        D8(s0,s1,s2,s3, a8 , hA[ 8]); D8(s0,s1,s2,s3, a9 , hA[ 9]);
        D8(s0,s1,s2,s3, a10, hA[10]); D8(s0,s1,s2,s3, a11, hA[11]);
        D8(s0,s1,s2,s3, a12, hA[12]); D8(s0,s1,s2,s3, a13, hA[13]);
        D8(s0,s1,s2,s3, a14, hA[14]); D8(s0,s1,s2,s3, a15, hA[15]);
        D8(c0,c1,c2,c3, w0 , h1r[ 0]); D8(c0,c1,c2,c3, w1 , h1r[ 1]);
        D8(c0,c1,c2,c3, w2 , h1r[ 2]); D8(c0,c1,c2,c3, w3 , h1r[ 3]);
        D8(c0,c1,c2,c3, w4 , h1r[ 4]); D8(c0,c1,c2,c3, w5 , h1r[ 5]);
        D8(c0,c1,c2,c3, w6 , h1r[ 6]); D8(c0,c1,c2,c3, w7 , h1r[ 7]);
        D8(c0,c1,c2,c3, w8 , h1r[ 8]); D8(c0,c1,c2,c3, w9 , h1r[ 9]);
        D8(c0,c1,c2,c3, w10, h1r[10]); D8(c0,c1,c2,c3, w11, h1r[11]);
        D8(c0,c1,c2,c3, w12, h1r[12]); D8(c0,c1,c2,c3, w13, h1r[13]);
        D8(c0,c1,c2,c3, w14, h1r[14]); D8(c0,c1,c2,c3, w15, h1r[15]);
      }
      ax = bi + ((s0 + s1) + (s2 + s3));
      ah = bh + ((c0 + c1) + (c2 + c3));
      if (g < 2*H_) rzW[g] = sigm_(ax + ah);
    }
    __syncthreads();                     // B2 — convergent, all threads
    if (act) {
      if (g >= 2*H_) {
        const int j = g - 2*H_;
        const float r = rzW[j], z = rzW[H_ + j];
        const float n = tanh_(ax + r * ah);
        const float hn = z * (hfW[j] - n) + n;     // (1-z)*n + z*h
        hfW[j] = hn;
        ((p & 1) ? hpW1 : hpW0)[j] = (_Float16)hn;
      }
      if (r0 && g < I_ && p + 1 < T_)
        ((_Float16*)xp[(p + 1) & 1])[g] = (_Float16)xnext;
    }
    __syncthreads();                     // B3 — convergent, all threads
  }

  // ---- final FC on h1(T-1) ----
  if (tid < O_) {
    float acc = fcb[tid];
    const float* wr = fcW + (size_t)tid * H_;
    for (int k = 0; k < H_; ++k) acc = fmaf(h1f[k], wr[k], acc);
    out[(size_t)b * O_ + tid] = acc;
  }
}

extern "C" void kernel_launch(void* const* d_in, const int* in_sizes, int n_in,
                              void* d_out, int out_size, void* d_ws, size_t ws_size,
                              hipStream_t stream) {
  const float* x    = (const float*)d_in[0];
  const float* Wih0 = (const float*)d_in[1];
  const float* Whh0 = (const float*)d_in[2];
  const float* bih0 = (const float*)d_in[3];
  const float* bhh0 = (const float*)d_in[4];
  const float* Wih1 = (const float*)d_in[5];
  const float* Whh1 = (const float*)d_in[6];
  const float* bih1 = (const float*)d_in[7];
  const float* bhh1 = (const float*)d_in[8];
  const float* fcW  = (const float*)d_in[9];
  const float* fcb  = (const float*)d_in[10];

  gru_net<<<dim3(B_), dim3(768), 0, stream>>>(
      x, Wih0, Whh0, bih0, bhh0, Wih1, Whh1, bih1, bhh1, fcW, fcb,
      (float*)d_out);
}